// Round 6
// baseline (500.769 us; speedup 1.0000x reference)
//
#include <hip/hip_runtime.h>

// Centroids: argmin_c ||latent[r] - coords[c]||^2, 131072 rows x 2048 coords, D=128.
//
// int8 hi/lo 3-pass via mfma_i32_16x16x64_i8 (R5, validated): a = qA(Ah+Al/128),
//   b = qB(Bh+Bl/128); dot = qA qB (I1 + I2/128), I1=Ah.Bh, I2=Ah.Bl+Al.Bh.
//   Dropped AlBl/16384 + residuals: ~1.5e-3 std << MARGIN_H 0.01.
// R6: occupancy 2->4 waves/SIMD (R5 was latency-bound: MfmaUtil 24, VALU 43,
//   wall 13.2k cyc/chunk/CU vs pipe demands 3.9k/5.7k).
//   - 128 rows/block (32-row waves, mt=0..1), grid 1024, launch_bounds(256,4).
//   - sqc LDS table evicted -> per-chunk global float2 loads (L2-resident;
//     issued AFTER the counted-vmcnt+barrier so the stage accounting holds).
//   - LDS 32KB/block -> 4 blocks/CU; A-frags 32 VGPR.
// Kept (validated R1-R5): gl_lds w=16 dbuf + counted vmcnt(4), de-phase entry
//   sleep (4-phase now), setprio(1) around MFMA, med3 second-best epilogue,
//   no-tiebreak butterfly, fp64 refine margin net.
// refine v2: 1024-thread blocks, 2 coords/thread (4x less per-row latency).
//
// ws layout (bytes): 0 qc2 (16KB) | 16384 counter | 32768 worklist (128KB) |
//                    262144 Bh (256KB) | 524288 Bl (256KB) | end 786432

constexpr int D = 128;
constexpr int C = 2048;
constexpr int NCH = 64;            // coords per chunk
constexpr int NCHUNKS = C / NCH;   // 32
constexpr float MARGIN_H = 0.01f;  // half-scale; i8 hi/lo ~6-sigma headroom
constexpr int WL_CAP = 32768;

constexpr size_t WS_CNT = 16384;
constexpr size_t WS_WL  = 32768;
constexpr size_t WS_BH  = 262144;
constexpr size_t WS_BL  = 524288;

typedef __attribute__((ext_vector_type(4))) int   i32x4;
typedef unsigned int u32;

__device__ __forceinline__ int pack4(int a0, int a1, int a2, int a3) {
    return (int)(((u32)a0 & 255u) | (((u32)a1 & 255u) << 8) |
                 (((u32)a2 & 255u) << 16) | (((u32)a3 & 255u) << 24));
}

// quantize v -> hi (|h|<=127), lo (|l|<=64): v = h*qa + l*qa/128 + eps
__device__ __forceinline__ void q2(float v, float qa, float inv, float inv128,
                                   int* h, int* l) {
    float hf = __builtin_rintf(v * inv);
    *h = (int)hf;
    float r = fmaf(-hf, qa, v);
    *l = (int)__builtin_rintf(r * inv128);
}

// async global->LDS, 16B per lane (wave-uniform base + lane*16: contiguous).
__device__ __forceinline__ void gl_lds16(const void* g, void* l) {
    __builtin_amdgcn_global_load_lds(
        (const __attribute__((address_space(1))) u32*)g,
        (__attribute__((address_space(3))) u32*)l, 16, 0, 0);
}

// ---------------- prep: int8 B images + {qB, -c2/2} ----------------
// 4 threads per coord; thread part p handles elems p*32..p*32+31 (granules
// g8 = 2p, 2p+1). Image granule placement: pos = g8 ^ (nl&7), nl = c&63.
__global__ void prep_coords(const float* __restrict__ coords,
                            signed char* __restrict__ Bh,
                            signed char* __restrict__ Bl,
                            float2* __restrict__ qc2, int* __restrict__ counter) {
    int t = blockIdx.x * blockDim.x + threadIdx.x;
    if (t == 0) *counter = 0;
    if (t >= C * 4) return;
    int c = t >> 2, p = t & 3;
    float v[32];
#pragma unroll
    for (int i = 0; i < 8; ++i)
        *(float4*)(v + i * 4) = *(const float4*)(coords + (size_t)c * D + p * 32 + i * 4);
    float amax = 0.f, ss = 0.f;
#pragma unroll
    for (int j = 0; j < 32; ++j) {
        amax = fmaxf(amax, fabsf(v[j]));
        ss = fmaf(v[j], v[j], ss);
    }
#pragma unroll
    for (int m = 1; m <= 2; m <<= 1) {
        amax = fmaxf(amax, __shfl_xor(amax, m, 64));
        ss += __shfl_xor(ss, m, 64);
    }
    float qb = fmaxf(amax, 1e-30f) * (1.f / 127.f);
    float inv = 127.f / fmaxf(amax, 1e-30f);
    float inv128 = inv * 128.f;

    int ch = c >> 6, nl = c & 63;
    size_t cbase = (size_t)ch * (NCH * 128) + (size_t)nl * 128;
#pragma unroll
    for (int g = 0; g < 2; ++g) {        // two 16-elem granules
        int g8 = p * 2 + g;
        int hw[4], lw[4];
#pragma unroll
        for (int w = 0; w < 4; ++w) {
            int h0, l0, h1, l1, h2, l2, h3, l3;
            q2(v[g * 16 + w * 4 + 0], qb, inv, inv128, &h0, &l0);
            q2(v[g * 16 + w * 4 + 1], qb, inv, inv128, &h1, &l1);
            q2(v[g * 16 + w * 4 + 2], qb, inv, inv128, &h2, &l2);
            q2(v[g * 16 + w * 4 + 3], qb, inv, inv128, &h3, &l3);
            hw[w] = pack4(h0, h1, h2, h3);
            lw[w] = pack4(l0, l1, l2, l3);
        }
        size_t off = cbase + (size_t)(g8 ^ (nl & 7)) * 16;
        *(i32x4*)(Bh + off) = (i32x4){hw[0], hw[1], hw[2], hw[3]};
        *(i32x4*)(Bl + off) = (i32x4){lw[0], lw[1], lw[2], lw[3]};
    }
    if (p == 0) qc2[c] = make_float2(qb, -0.5f * ss);
}

// ---------------- main kernel ----------------

__global__ __launch_bounds__(256, 4) void centroid_fast(
        const float* __restrict__ latent,
        const signed char* __restrict__ Bh_img,
        const signed char* __restrict__ Bl_img,
        const float2* __restrict__ qc2g,
        int* __restrict__ out,
        int* __restrict__ counter,
        int* __restrict__ worklist) {
    // dbuf 2x8KB hi + 2x8KB lo = 32 KB -> 4 blocks/CU (4 waves/SIMD)
    __shared__ __align__(16) signed char Bh[2][NCH * 128], Bl[2][NCH * 128];

    const int tid  = threadIdx.x;
    const int wid  = tid >> 6;            // wave 0..3 -> rows wid*32..wid*32+31
    const int lane = tid & 63;
    const int q    = lane >> 4, lr = lane & 15;
    const int row_block = blockIdx.x * 128;

    // de-phase co-resident blocks: 4 phases, ~quarter-chunk steps
    {
        int ph = (blockIdx.x ^ (blockIdx.x >> 8)) & 3;
        for (int i = 0; i < ph * 2; ++i) __builtin_amdgcn_s_sleep(8);
    }

    // ---- prologue: stage chunk 0 (async) ----
#pragma unroll
    for (int i = 0; i < 2; ++i) {
        int e = (i * 256 + tid) * 16;
        gl_lds16(Bh_img + e, &Bh[0][e]);
        gl_lds16(Bl_img + e, &Bl[0][e]);
    }

    // ---- A fragments: int8 hi/lo. Lane holds rows wid*32+mt*16+lr,
    // k = kstep*64 + q*16 + 0..15 -> i32x4 per (mt,kstep). 32 VGPRs.
    i32x4 Ah[2][2], Al[2][2];
    float qAr[2][4];                     // qA for epilogue rows mt*16+q*4+r
#pragma unroll
    for (int mt = 0; mt < 2; ++mt) {
        const float* rp = latent + (size_t)(row_block + wid * 32 + mt * 16 + lr) * D;
        float v[32];
#pragma unroll
        for (int ks = 0; ks < 2; ++ks)
#pragma unroll
            for (int i = 0; i < 4; ++i)
                *(float4*)(v + ks * 16 + i * 4) =
                    *(const float4*)(rp + ks * 64 + q * 16 + i * 4);
        float amax = 0.f;
#pragma unroll
        for (int j = 0; j < 32; ++j) amax = fmaxf(amax, fabsf(v[j]));
        amax = fmaxf(amax, __shfl_xor(amax, 16, 64));
        amax = fmaxf(amax, __shfl_xor(amax, 32, 64));
        float qa = fmaxf(amax, 1e-30f) * (1.f / 127.f);
        float inv = 127.f / fmaxf(amax, 1e-30f);
        float inv128 = inv * 128.f;
#pragma unroll
        for (int ks = 0; ks < 2; ++ks) {
            int hw[4], lw[4];
#pragma unroll
            for (int w = 0; w < 4; ++w) {
                int h0, l0, h1, l1, h2, l2, h3, l3;
                q2(v[ks * 16 + w * 4 + 0], qa, inv, inv128, &h0, &l0);
                q2(v[ks * 16 + w * 4 + 1], qa, inv, inv128, &h1, &l1);
                q2(v[ks * 16 + w * 4 + 2], qa, inv, inv128, &h2, &l2);
                q2(v[ks * 16 + w * 4 + 3], qa, inv, inv128, &h3, &l3);
                hw[w] = pack4(h0, h1, h2, h3);
                lw[w] = pack4(l0, l1, l2, l3);
            }
            Ah[mt][ks] = (i32x4){hw[0], hw[1], hw[2], hw[3]};
            Al[mt][ks] = (i32x4){lw[0], lw[1], lw[2], lw[3]};
        }
        // broadcast qa from lr-lanes to (q*4+r) epilogue rows
#pragma unroll
        for (int r = 0; r < 4; ++r)
            qAr[mt][r] = __shfl(qa, (lane & 48) | (q * 4 + r), 64);
    }

    // argmax state over a = dot - 0.5*c2 (== argmin distance), 8 slots
    float b1[8], b2[8];
    int   bidx[8];
#pragma unroll
    for (int s = 0; s < 8; ++s) { b1[s] = -3.4e38f; b2[s] = -3.4e38f; bidx[s] = 0; }

    __syncthreads();   // full drain: chunk-0 stage + A loads visible

    for (int ch = 0; ch < NCHUNKS; ++ch) {
        const int buf = ch & 1;
        const int chbase = ch * NCH;
        // issue next chunk's stage FIRST, then counted wait on current's 4.
        // (qc loads happen strictly AFTER this asm -> can't pollute the count.)
        if (ch + 1 < NCHUNKS) {
            const signed char* sh = Bh_img + (size_t)(ch + 1) * (NCH * 128);
            const signed char* sl = Bl_img + (size_t)(ch + 1) * (NCH * 128);
#pragma unroll
            for (int i = 0; i < 2; ++i) {
                int e = (i * 256 + tid) * 16;
                gl_lds16(sh + e, &Bh[buf ^ 1][e]);
                gl_lds16(sl + e, &Bl[buf ^ 1][e]);
            }
            asm volatile("s_waitcnt vmcnt(4)" ::: "memory");
        } else {
            asm volatile("s_waitcnt vmcnt(0)" ::: "memory");
        }
        __builtin_amdgcn_s_barrier();

        // per-chunk {qB, -c2/2}: L1/L2-resident 16KB table, 4 loads/lane,
        // consumed in each nt's epilogue (drained well before next vmcnt).
        float2 qcv[4];
#pragma unroll
        for (int nt = 0; nt < 4; ++nt) qcv[nt] = qc2g[chbase + nt * 16 + lr];

#pragma unroll
        for (int nt = 0; nt < 4; ++nt) {
            const int nl = nt * 16 + lr;
            i32x4 I1[2], I2[2];
#pragma unroll
            for (int mt = 0; mt < 2; ++mt) {
                I1[mt] = (i32x4){0, 0, 0, 0};
                I2[mt] = (i32x4){0, 0, 0, 0};
            }
            __builtin_amdgcn_s_setprio(1);
#pragma unroll
            for (int ks = 0; ks < 2; ++ks) {
                const int e = nl * 128 + (((ks << 2) | q) ^ (lr & 7)) * 16;
                i32x4 bh = *(const i32x4*)(&Bh[buf][e]);
                i32x4 bl = *(const i32x4*)(&Bl[buf][e]);
#pragma unroll
                for (int mt = 0; mt < 2; ++mt)
                    I1[mt] = __builtin_amdgcn_mfma_i32_16x16x64_i8(Ah[mt][ks], bh, I1[mt], 0, 0, 0);
#pragma unroll
                for (int mt = 0; mt < 2; ++mt)
                    I2[mt] = __builtin_amdgcn_mfma_i32_16x16x64_i8(Ah[mt][ks], bl, I2[mt], 0, 0, 0);
#pragma unroll
                for (int mt = 0; mt < 2; ++mt)
                    I2[mt] = __builtin_amdgcn_mfma_i32_16x16x64_i8(Al[mt][ks], bh, I2[mt], 0, 0, 0);
            }
            __builtin_amdgcn_s_setprio(0);
            const int n_global = chbase + nl;
            const float2 qc = qcv[nt];
#pragma unroll
            for (int mt = 0; mt < 2; ++mt)
#pragma unroll
                for (int r = 0; r < 4; ++r) {
                    int slot = mt * 4 + r;
                    float x = fmaf((float)I2[mt][r], 0.0078125f, (float)I1[mt][r]);
                    float a = fmaf(qAr[mt][r], x * qc.x, qc.y);
                    b2[slot]   = __builtin_amdgcn_fmed3f(a, b1[slot], b2[slot]);
                    bool gt    = a > b1[slot];
                    b1[slot]   = fmaxf(a, b1[slot]);
                    bidx[slot] = gt ? n_global : bidx[slot];
                }
        }
        __builtin_amdgcn_s_barrier();   // all reads of buf done before restage
    }

    // butterfly over the 16 col-residue lanes (max semantics, no tie-break:
    // ties -> gap 0 < margin -> exact refine resolves)
#pragma unroll
    for (int m = 1; m <= 8; m <<= 1) {
#pragma unroll
        for (int s = 0; s < 8; ++s) {
            float oa = __shfl_xor(b1[s], m, 64);
            float ob = __shfl_xor(b2[s], m, 64);
            int   oi = __shfl_xor(bidx[s], m, 64);
            float mn = fminf(b1[s], oa);
            b2[s] = fmaxf(fmaxf(b2[s], ob), mn);
            bool take = oa > b1[s];
            b1[s]   = take ? oa : b1[s];
            bidx[s] = take ? oi : bidx[s];
        }
    }
    // slot s canonical in lane lr==s; row = wid*32 + (s>>2)*16 + q*4 + (s&3)
#pragma unroll
    for (int s = 0; s < 8; ++s) {
        if (lr == s) {
            int row = row_block + wid * 32 + (s >> 2) * 16 + q * 4 + (s & 3);
            out[row] = bidx[s];
            if (b1[s] - b2[s] < MARGIN_H) {
                int w = atomicAdd(counter, 1);
                if (w < WL_CAP) worklist[w] = row;
            }
        }
    }
}

// ---------------- fp64 refine (v2: 1024 threads, 2 coords/thread) ----------------

__global__ __launch_bounds__(1024) void refine_fp64(
        const float* __restrict__ latent, const float* __restrict__ coords,
        const int* __restrict__ worklist, const int* __restrict__ counter,
        int wl_cap, int* __restrict__ out) {
    __shared__ float  xs[D];
    __shared__ double rv[1024];
    __shared__ int    ri[1024];

    int n = *counter;
    if (n > wl_cap) n = wl_cap;

    for (int wi = blockIdx.x; wi < n; wi += gridDim.x) {
        int row = worklist[wi];
        if (threadIdx.x < D)
            xs[threadIdx.x] = latent[(size_t)row * D + threadIdx.x];
        __syncthreads();

        double best = 1.0e300;
        int    bix  = 0;
        for (int c = threadIdx.x; c < C; c += 1024) {
            const float4* cp = (const float4*)(coords + (size_t)c * D);
            double s0 = 0.0, s1 = 0.0, s2 = 0.0, s3 = 0.0;
#pragma unroll 8
            for (int k4 = 0; k4 < 32; ++k4) {
                float4 v = cp[k4];
                double d0 = (double)xs[k4 * 4 + 0] - (double)v.x;
                double d1 = (double)xs[k4 * 4 + 1] - (double)v.y;
                double d2 = (double)xs[k4 * 4 + 2] - (double)v.z;
                double d3 = (double)xs[k4 * 4 + 3] - (double)v.w;
                s0 = fma(d0, d0, s0); s1 = fma(d1, d1, s1);
                s2 = fma(d2, d2, s2); s3 = fma(d3, d3, s3);
            }
            double s = (s0 + s1) + (s2 + s3);
            if (s < best) { best = s; bix = c; }
        }
        rv[threadIdx.x] = best;
        ri[threadIdx.x] = bix;
        __syncthreads();
        for (int off = 512; off > 0; off >>= 1) {
            if (threadIdx.x < off) {
                double ov = rv[threadIdx.x + off];
                int    oi = ri[threadIdx.x + off];
                if (ov < rv[threadIdx.x] ||
                    (ov == rv[threadIdx.x] && oi < ri[threadIdx.x])) {
                    rv[threadIdx.x] = ov;
                    ri[threadIdx.x] = oi;
                }
            }
            __syncthreads();
        }
        if (threadIdx.x == 0) out[row] = ri[0];
        __syncthreads();
    }
}

extern "C" void kernel_launch(void* const* d_in, const int* in_sizes, int n_in,
                              void* d_out, int out_size, void* d_ws, size_t ws_size,
                              hipStream_t stream) {
    const float* latent = (const float*)d_in[0];
    const float* coords = (const float*)d_in[1];
    int*         out    = (int*)d_out;

    char* ws = (char*)d_ws;
    float2* qc2    = (float2*)ws;
    int*    counter = (int*)(ws + WS_CNT);
    int*    wl      = (int*)(ws + WS_WL);
    signed char* Bh = (signed char*)(ws + WS_BH);
    signed char* Bl = (signed char*)(ws + WS_BL);
    const int n_rows = in_sizes[0] / D;   // 131072

    prep_coords<<<(C * 4) / 256, 256, 0, stream>>>(coords, Bh, Bl, qc2, counter);
    centroid_fast<<<n_rows / 128, 256, 0, stream>>>(latent, Bh, Bl, qc2, out,
                                                    counter, wl);
    refine_fp64<<<608, 1024, 0, stream>>>(latent, coords, wl, counter, WL_CAP, out);
}

// Round 7
// 276.317 us; speedup vs baseline: 1.8123x; 1.8123x over previous
//
#include <hip/hip_runtime.h>

// Centroids: argmin_c ||latent[r] - coords[c]||^2, 131072 rows x 2048 coords, D=128.
//
// int8 hi/lo 3-pass via mfma_i32_16x16x64_i8 (R5, validated): a = qA(Ah+Al/128),
//   b = qB(Bh+Bl/128); dot = qA qB (I1 + I2/128), I1=Ah.Bh, I2=Ah.Bl+Al.Bh.
//   Dropped AlBl/16384 + residuals: ~1.5e-3 std << MARGIN_H 0.01.
// R6 geometry (validated: occupancy 44% reached): 128 rows/block (32-row waves,
//   mt=0..1), grid 1024, LDS 32KB -> 4 blocks/CU; sqc table evicted to per-chunk
//   global float2 loads (L2-resident, issued after the counted vmcnt+barrier).
// R7 FIX: launch_bounds(256,4) made the allocator budget 64 VGPRs (observed
//   VGPR_Count=64, WRITE_SIZE 410 MB scratch). Body needs ~100-120 live.
//   -> launch_bounds(256,2) (cap ~256, known-good R1-R5). Hardware occupancy
//   is then LDS/grid-limited at 4 blocks/CU as long as usage <= 128.
// Kept (validated R1-R5): gl_lds w=16 dbuf + counted vmcnt(4), de-phase entry
//   sleep (4-phase), setprio(1) around MFMA, med3 second-best epilogue,
//   no-tiebreak butterfly, fp64 refine margin net.
// refine v2: 1024-thread blocks, 2 coords/thread.
//
// ws layout (bytes): 0 qc2 (16KB) | 16384 counter | 32768 worklist (128KB) |
//                    262144 Bh (256KB) | 524288 Bl (256KB) | end 786432

constexpr int D = 128;
constexpr int C = 2048;
constexpr int NCH = 64;            // coords per chunk
constexpr int NCHUNKS = C / NCH;   // 32
constexpr float MARGIN_H = 0.01f;  // half-scale; i8 hi/lo ~6-sigma headroom
constexpr int WL_CAP = 32768;

constexpr size_t WS_CNT = 16384;
constexpr size_t WS_WL  = 32768;
constexpr size_t WS_BH  = 262144;
constexpr size_t WS_BL  = 524288;

typedef __attribute__((ext_vector_type(4))) int   i32x4;
typedef unsigned int u32;

__device__ __forceinline__ int pack4(int a0, int a1, int a2, int a3) {
    return (int)(((u32)a0 & 255u) | (((u32)a1 & 255u) << 8) |
                 (((u32)a2 & 255u) << 16) | (((u32)a3 & 255u) << 24));
}

// quantize v -> hi (|h|<=127), lo (|l|<=64): v = h*qa + l*qa/128 + eps
__device__ __forceinline__ void q2(float v, float qa, float inv, float inv128,
                                   int* h, int* l) {
    float hf = __builtin_rintf(v * inv);
    *h = (int)hf;
    float r = fmaf(-hf, qa, v);
    *l = (int)__builtin_rintf(r * inv128);
}

// async global->LDS, 16B per lane (wave-uniform base + lane*16: contiguous).
__device__ __forceinline__ void gl_lds16(const void* g, void* l) {
    __builtin_amdgcn_global_load_lds(
        (const __attribute__((address_space(1))) u32*)g,
        (__attribute__((address_space(3))) u32*)l, 16, 0, 0);
}

// ---------------- prep: int8 B images + {qB, -c2/2} ----------------
// 4 threads per coord; thread part p handles elems p*32..p*32+31 (granules
// g8 = 2p, 2p+1). Image granule placement: pos = g8 ^ (nl&7), nl = c&63.
__global__ void prep_coords(const float* __restrict__ coords,
                            signed char* __restrict__ Bh,
                            signed char* __restrict__ Bl,
                            float2* __restrict__ qc2, int* __restrict__ counter) {
    int t = blockIdx.x * blockDim.x + threadIdx.x;
    if (t == 0) *counter = 0;
    if (t >= C * 4) return;
    int c = t >> 2, p = t & 3;
    float v[32];
#pragma unroll
    for (int i = 0; i < 8; ++i)
        *(float4*)(v + i * 4) = *(const float4*)(coords + (size_t)c * D + p * 32 + i * 4);
    float amax = 0.f, ss = 0.f;
#pragma unroll
    for (int j = 0; j < 32; ++j) {
        amax = fmaxf(amax, fabsf(v[j]));
        ss = fmaf(v[j], v[j], ss);
    }
#pragma unroll
    for (int m = 1; m <= 2; m <<= 1) {
        amax = fmaxf(amax, __shfl_xor(amax, m, 64));
        ss += __shfl_xor(ss, m, 64);
    }
    float qb = fmaxf(amax, 1e-30f) * (1.f / 127.f);
    float inv = 127.f / fmaxf(amax, 1e-30f);
    float inv128 = inv * 128.f;

    int ch = c >> 6, nl = c & 63;
    size_t cbase = (size_t)ch * (NCH * 128) + (size_t)nl * 128;
#pragma unroll
    for (int g = 0; g < 2; ++g) {        // two 16-elem granules
        int g8 = p * 2 + g;
        int hw[4], lw[4];
#pragma unroll
        for (int w = 0; w < 4; ++w) {
            int h0, l0, h1, l1, h2, l2, h3, l3;
            q2(v[g * 16 + w * 4 + 0], qb, inv, inv128, &h0, &l0);
            q2(v[g * 16 + w * 4 + 1], qb, inv, inv128, &h1, &l1);
            q2(v[g * 16 + w * 4 + 2], qb, inv, inv128, &h2, &l2);
            q2(v[g * 16 + w * 4 + 3], qb, inv, inv128, &h3, &l3);
            hw[w] = pack4(h0, h1, h2, h3);
            lw[w] = pack4(l0, l1, l2, l3);
        }
        size_t off = cbase + (size_t)(g8 ^ (nl & 7)) * 16;
        *(i32x4*)(Bh + off) = (i32x4){hw[0], hw[1], hw[2], hw[3]};
        *(i32x4*)(Bl + off) = (i32x4){lw[0], lw[1], lw[2], lw[3]};
    }
    if (p == 0) qc2[c] = make_float2(qb, -0.5f * ss);
}

// ---------------- main kernel ----------------

__global__ __launch_bounds__(256, 2) void centroid_fast(
        const float* __restrict__ latent,
        const signed char* __restrict__ Bh_img,
        const signed char* __restrict__ Bl_img,
        const float2* __restrict__ qc2g,
        int* __restrict__ out,
        int* __restrict__ counter,
        int* __restrict__ worklist) {
    // dbuf 2x8KB hi + 2x8KB lo = 32 KB -> 4 blocks/CU if VGPR usage <= 128
    __shared__ __align__(16) signed char Bh[2][NCH * 128], Bl[2][NCH * 128];

    const int tid  = threadIdx.x;
    const int wid  = tid >> 6;            // wave 0..3 -> rows wid*32..wid*32+31
    const int lane = tid & 63;
    const int q    = lane >> 4, lr = lane & 15;
    const int row_block = blockIdx.x * 128;

    // de-phase co-resident blocks: 4 phases, ~quarter-chunk steps
    {
        int ph = (blockIdx.x ^ (blockIdx.x >> 8)) & 3;
        for (int i = 0; i < ph * 2; ++i) __builtin_amdgcn_s_sleep(8);
    }

    // ---- prologue: stage chunk 0 (async) ----
#pragma unroll
    for (int i = 0; i < 2; ++i) {
        int e = (i * 256 + tid) * 16;
        gl_lds16(Bh_img + e, &Bh[0][e]);
        gl_lds16(Bl_img + e, &Bl[0][e]);
    }

    // ---- A fragments: int8 hi/lo. Lane holds rows wid*32+mt*16+lr,
    // k = kstep*64 + q*16 + 0..15 -> i32x4 per (mt,kstep). 32 VGPRs.
    i32x4 Ah[2][2], Al[2][2];
    float qAr[2][4];                     // qA for epilogue rows mt*16+q*4+r
#pragma unroll
    for (int mt = 0; mt < 2; ++mt) {
        const float* rp = latent + (size_t)(row_block + wid * 32 + mt * 16 + lr) * D;
        float v[32];
#pragma unroll
        for (int ks = 0; ks < 2; ++ks)
#pragma unroll
            for (int i = 0; i < 4; ++i)
                *(float4*)(v + ks * 16 + i * 4) =
                    *(const float4*)(rp + ks * 64 + q * 16 + i * 4);
        float amax = 0.f;
#pragma unroll
        for (int j = 0; j < 32; ++j) amax = fmaxf(amax, fabsf(v[j]));
        amax = fmaxf(amax, __shfl_xor(amax, 16, 64));
        amax = fmaxf(amax, __shfl_xor(amax, 32, 64));
        float qa = fmaxf(amax, 1e-30f) * (1.f / 127.f);
        float inv = 127.f / fmaxf(amax, 1e-30f);
        float inv128 = inv * 128.f;
#pragma unroll
        for (int ks = 0; ks < 2; ++ks) {
            int hw[4], lw[4];
#pragma unroll
            for (int w = 0; w < 4; ++w) {
                int h0, l0, h1, l1, h2, l2, h3, l3;
                q2(v[ks * 16 + w * 4 + 0], qa, inv, inv128, &h0, &l0);
                q2(v[ks * 16 + w * 4 + 1], qa, inv, inv128, &h1, &l1);
                q2(v[ks * 16 + w * 4 + 2], qa, inv, inv128, &h2, &l2);
                q2(v[ks * 16 + w * 4 + 3], qa, inv, inv128, &h3, &l3);
                hw[w] = pack4(h0, h1, h2, h3);
                lw[w] = pack4(l0, l1, l2, l3);
            }
            Ah[mt][ks] = (i32x4){hw[0], hw[1], hw[2], hw[3]};
            Al[mt][ks] = (i32x4){lw[0], lw[1], lw[2], lw[3]};
        }
        // broadcast qa from lr-lanes to (q*4+r) epilogue rows
#pragma unroll
        for (int r = 0; r < 4; ++r)
            qAr[mt][r] = __shfl(qa, (lane & 48) | (q * 4 + r), 64);
    }

    // argmax state over a = dot - 0.5*c2 (== argmin distance), 8 slots
    float b1[8], b2[8];
    int   bidx[8];
#pragma unroll
    for (int s = 0; s < 8; ++s) { b1[s] = -3.4e38f; b2[s] = -3.4e38f; bidx[s] = 0; }

    __syncthreads();   // full drain: chunk-0 stage + A loads visible

    for (int ch = 0; ch < NCHUNKS; ++ch) {
        const int buf = ch & 1;
        const int chbase = ch * NCH;
        // issue next chunk's stage FIRST, then counted wait on current's 4.
        // (qc loads happen strictly AFTER this asm -> can't pollute the count.)
        if (ch + 1 < NCHUNKS) {
            const signed char* sh = Bh_img + (size_t)(ch + 1) * (NCH * 128);
            const signed char* sl = Bl_img + (size_t)(ch + 1) * (NCH * 128);
#pragma unroll
            for (int i = 0; i < 2; ++i) {
                int e = (i * 256 + tid) * 16;
                gl_lds16(sh + e, &Bh[buf ^ 1][e]);
                gl_lds16(sl + e, &Bl[buf ^ 1][e]);
            }
            asm volatile("s_waitcnt vmcnt(4)" ::: "memory");
        } else {
            asm volatile("s_waitcnt vmcnt(0)" ::: "memory");
        }
        __builtin_amdgcn_s_barrier();

        // per-chunk {qB, -c2/2}: L1/L2-resident 16KB table, 4 loads/lane,
        // consumed in each nt's epilogue (drained well before next vmcnt).
        float2 qcv[4];
#pragma unroll
        for (int nt = 0; nt < 4; ++nt) qcv[nt] = qc2g[chbase + nt * 16 + lr];

#pragma unroll
        for (int nt = 0; nt < 4; ++nt) {
            const int nl = nt * 16 + lr;
            i32x4 I1[2], I2[2];
#pragma unroll
            for (int mt = 0; mt < 2; ++mt) {
                I1[mt] = (i32x4){0, 0, 0, 0};
                I2[mt] = (i32x4){0, 0, 0, 0};
            }
            __builtin_amdgcn_s_setprio(1);
#pragma unroll
            for (int ks = 0; ks < 2; ++ks) {
                const int e = nl * 128 + (((ks << 2) | q) ^ (lr & 7)) * 16;
                i32x4 bh = *(const i32x4*)(&Bh[buf][e]);
                i32x4 bl = *(const i32x4*)(&Bl[buf][e]);
#pragma unroll
                for (int mt = 0; mt < 2; ++mt)
                    I1[mt] = __builtin_amdgcn_mfma_i32_16x16x64_i8(Ah[mt][ks], bh, I1[mt], 0, 0, 0);
#pragma unroll
                for (int mt = 0; mt < 2; ++mt)
                    I2[mt] = __builtin_amdgcn_mfma_i32_16x16x64_i8(Ah[mt][ks], bl, I2[mt], 0, 0, 0);
#pragma unroll
                for (int mt = 0; mt < 2; ++mt)
                    I2[mt] = __builtin_amdgcn_mfma_i32_16x16x64_i8(Al[mt][ks], bh, I2[mt], 0, 0, 0);
            }
            __builtin_amdgcn_s_setprio(0);
            const int n_global = chbase + nl;
            const float2 qc = qcv[nt];
#pragma unroll
            for (int mt = 0; mt < 2; ++mt)
#pragma unroll
                for (int r = 0; r < 4; ++r) {
                    int slot = mt * 4 + r;
                    float x = fmaf((float)I2[mt][r], 0.0078125f, (float)I1[mt][r]);
                    float a = fmaf(qAr[mt][r], x * qc.x, qc.y);
                    b2[slot]   = __builtin_amdgcn_fmed3f(a, b1[slot], b2[slot]);
                    bool gt    = a > b1[slot];
                    b1[slot]   = fmaxf(a, b1[slot]);
                    bidx[slot] = gt ? n_global : bidx[slot];
                }
        }
        __builtin_amdgcn_s_barrier();   // all reads of buf done before restage
    }

    // butterfly over the 16 col-residue lanes (max semantics, no tie-break:
    // ties -> gap 0 < margin -> exact refine resolves)
#pragma unroll
    for (int m = 1; m <= 8; m <<= 1) {
#pragma unroll
        for (int s = 0; s < 8; ++s) {
            float oa = __shfl_xor(b1[s], m, 64);
            float ob = __shfl_xor(b2[s], m, 64);
            int   oi = __shfl_xor(bidx[s], m, 64);
            float mn = fminf(b1[s], oa);
            b2[s] = fmaxf(fmaxf(b2[s], ob), mn);
            bool take = oa > b1[s];
            b1[s]   = take ? oa : b1[s];
            bidx[s] = take ? oi : bidx[s];
        }
    }
    // slot s canonical in lane lr==s; row = wid*32 + (s>>2)*16 + q*4 + (s&3)
#pragma unroll
    for (int s = 0; s < 8; ++s) {
        if (lr == s) {
            int row = row_block + wid * 32 + (s >> 2) * 16 + q * 4 + (s & 3);
            out[row] = bidx[s];
            if (b1[s] - b2[s] < MARGIN_H) {
                int w = atomicAdd(counter, 1);
                if (w < WL_CAP) worklist[w] = row;
            }
        }
    }
}

// ---------------- fp64 refine (v2: 1024 threads, 2 coords/thread) ----------------

__global__ __launch_bounds__(1024) void refine_fp64(
        const float* __restrict__ latent, const float* __restrict__ coords,
        const int* __restrict__ worklist, const int* __restrict__ counter,
        int wl_cap, int* __restrict__ out) {
    __shared__ float  xs[D];
    __shared__ double rv[1024];
    __shared__ int    ri[1024];

    int n = *counter;
    if (n > wl_cap) n = wl_cap;

    for (int wi = blockIdx.x; wi < n; wi += gridDim.x) {
        int row = worklist[wi];
        if (threadIdx.x < D)
            xs[threadIdx.x] = latent[(size_t)row * D + threadIdx.x];
        __syncthreads();

        double best = 1.0e300;
        int    bix  = 0;
        for (int c = threadIdx.x; c < C; c += 1024) {
            const float4* cp = (const float4*)(coords + (size_t)c * D);
            double s0 = 0.0, s1 = 0.0, s2 = 0.0, s3 = 0.0;
#pragma unroll 8
            for (int k4 = 0; k4 < 32; ++k4) {
                float4 v = cp[k4];
                double d0 = (double)xs[k4 * 4 + 0] - (double)v.x;
                double d1 = (double)xs[k4 * 4 + 1] - (double)v.y;
                double d2 = (double)xs[k4 * 4 + 2] - (double)v.z;
                double d3 = (double)xs[k4 * 4 + 3] - (double)v.w;
                s0 = fma(d0, d0, s0); s1 = fma(d1, d1, s1);
                s2 = fma(d2, d2, s2); s3 = fma(d3, d3, s3);
            }
            double s = (s0 + s1) + (s2 + s3);
            if (s < best) { best = s; bix = c; }
        }
        rv[threadIdx.x] = best;
        ri[threadIdx.x] = bix;
        __syncthreads();
        for (int off = 512; off > 0; off >>= 1) {
            if (threadIdx.x < off) {
                double ov = rv[threadIdx.x + off];
                int    oi = ri[threadIdx.x + off];
                if (ov < rv[threadIdx.x] ||
                    (ov == rv[threadIdx.x] && oi < ri[threadIdx.x])) {
                    rv[threadIdx.x] = ov;
                    ri[threadIdx.x] = oi;
                }
            }
            __syncthreads();
        }
        if (threadIdx.x == 0) out[row] = ri[0];
        __syncthreads();
    }
}

extern "C" void kernel_launch(void* const* d_in, const int* in_sizes, int n_in,
                              void* d_out, int out_size, void* d_ws, size_t ws_size,
                              hipStream_t stream) {
    const float* latent = (const float*)d_in[0];
    const float* coords = (const float*)d_in[1];
    int*         out    = (int*)d_out;

    char* ws = (char*)d_ws;
    float2* qc2    = (float2*)ws;
    int*    counter = (int*)(ws + WS_CNT);
    int*    wl      = (int*)(ws + WS_WL);
    signed char* Bh = (signed char*)(ws + WS_BH);
    signed char* Bl = (signed char*)(ws + WS_BL);
    const int n_rows = in_sizes[0] / D;   // 131072

    prep_coords<<<(C * 4) / 256, 256, 0, stream>>>(coords, Bh, Bl, qc2, counter);
    centroid_fast<<<n_rows / 128, 256, 0, stream>>>(latent, Bh, Bl, qc2, out,
                                                    counter, wl);
    refine_fp64<<<608, 1024, 0, stream>>>(latent, coords, wl, counter, WL_CAP, out);
}